// Round 10
// baseline (427.141 us; speedup 1.0000x reference)
//
#include <hip/hip_runtime.h>
#include <hip/hip_bf16.h>
#include <stdint.h>

#define N 8192
#define D 128
#define NCHUNK 16
#define CHUNK (N / NCHUNK)      // 512 cols per chunk
#define RT 128                  // rows per block (4 waves x 32)
#define CT 64                   // cols per LDS tile
#define NTILES (CHUNK / CT)     // 8
#define NBLK (N / RT * NCHUNK)  // 1024 main blocks

typedef short bf16x8 __attribute__((ext_vector_type(8)));
typedef float f32x4 __attribute__((ext_vector_type(4)));
typedef unsigned int uint32;

// ---- workspace layout (bytes) ----
#define OFF_ACC   0u                          // [0] float S_sum, [4] uint32 C_count
#define OFF_SQ2   1024u                       // 8192 floats
#define OFF_BCNT  (OFF_SQ2 + N * 4u)         // NBLK uint32 per-block negative counts
#define OFF_M     (OFF_BCNT + NBLK * 4u)      // NCHUNK*N floats (per-chunk row max)
#define OFF_L     (OFF_M + NCHUNK * N * 4u)
#define OFF_S     (OFF_L + NCHUNK * N * 4u)
#define OFF_F1    (OFF_S + NCHUNK * N * 4u)   // feat1 bf16
#define OFF_F2    (OFF_F1 + N * D * 2u)       // feat2 bf16

// Convert feats to bf16; compute sq2[j] = ||feat2_j||^2.
__global__ __launch_bounds__(256)
void prep_kernel(const float* __restrict__ f1, const float* __restrict__ f2,
                 unsigned short* __restrict__ f1b, unsigned short* __restrict__ f2b,
                 float* __restrict__ sq2) {
    const int w    = blockIdx.x * 4 + (threadIdx.x >> 6);  // 0..1023
    const int lane = threadIdx.x & 63;
    for (int row = w; row < N; row += 1024) {
        float a0 = f1[row * D + lane];
        float a1 = f1[row * D + 64 + lane];
        float b0 = f2[row * D + lane];
        float b1 = f2[row * D + 64 + lane];
        __hip_bfloat16 t;
        t = __float2bfloat16(a0); f1b[row * D + lane]      = *(unsigned short*)&t;
        t = __float2bfloat16(a1); f1b[row * D + 64 + lane] = *(unsigned short*)&t;
        t = __float2bfloat16(b0); f2b[row * D + lane]      = *(unsigned short*)&t;
        t = __float2bfloat16(b1); f2b[row * D + 64 + lane] = *(unsigned short*)&t;
        float ss = b0 * b0 + b1 * b1;
        #pragma unroll
        for (int off = 32; off > 0; off >>= 1) ss += __shfl_xor(ss, off);
        if (lane == 0) sq2[row] = ss;
    }
}

// FUSED GEMM + online softmax + raw-simi masking + negative count.
// ROUND 10: one-tile software pipeline. The compiler emits s_waitcnt vmcnt(0)
// before EVERY s_barrier, so round 9's "issue masks before the barrier" gave
// ZERO overlap (each tile paid a serial HBM drain). Now ALL tile-(t+1) global
// loads (masks, staging regs, sqv) issue AFTER barrier B of tile t and are
// consumed after barrier B of tile t+1 — each load flies under a full compute
// phase, and the only barrier that drains it is the one that must anyway.
// Column permutation c(q)=4*(q&15)+(q>>4): acc[cf] lane lo <-> global col
// cbase+4*lo+cf -> one int4 simi load per row per tile; softmax perm-invariant.
__global__ __launch_bounds__(256)
void main_kernel(const unsigned short* __restrict__ f1b,
                 const unsigned short* __restrict__ f2b,
                 const float* __restrict__ sq2,
                 const int* __restrict__ simi,
                 float* __restrict__ pm, float* __restrict__ pl, float* __restrict__ ps,
                 uint32* __restrict__ blockcnt) {
    __shared__ unsigned short ldsB[CT * D];  // 16 KB, XOR-swizzled
    __shared__ uint32 cred[4];

    const int tid  = threadIdx.x;
    const int wave = tid >> 6;
    const int lane = tid & 63;
    const int lo   = lane & 15;
    const int hi   = lane >> 4;

    const int rowtile = blockIdx.x;       // 0..63
    const int chunk   = blockIdx.y;       // 0..15
    const int rbase   = rowtile * RT + wave * 32;
    const int cbase0  = chunk * CHUNK;

    // A fragments: 2 sets of 16 rows, full K=128, resident for the sweep.
    bf16x8 afrag[2][4];
    #pragma unroll
    for (int a = 0; a < 2; a++) {
        const unsigned short* ap = f1b + (size_t)(rbase + a * 16 + lo) * D + hi * 8;
        #pragma unroll
        for (int kk = 0; kk < 4; kk++)
            afrag[a][kk] = *reinterpret_cast<const bf16x8*>(ap + kk * 32);
    }

    const int sq_ = (tid >> 4);           // staging: position within 16-group
    const int sg_ = tid & 15;             // staging: 16B chunk index
    // staging source pointers (col c(q) fixed per thread per it)
    const unsigned short* stg_p[4];
    #pragma unroll
    for (int it = 0; it < 4; it++) {
        int q = it * 16 + sq_;
        int c = 4 * (q & 15) + (q >> 4);
        stg_p[it] = f2b + (size_t)(cbase0 + c) * D + sg_ * 8;
    }
    unsigned short* lds_p[4];
    #pragma unroll
    for (int it = 0; it < 4; it++) {
        int q = it * 16 + sq_;
        lds_p[it] = ldsB + q * D + ((sg_ ^ (q & 15)) * 8);
    }

    // simi pointer: rows rbase+hi*4 (+a*16+r), cols cbase0 + 4*lo
    const int* simi_p = simi + (size_t)(rbase + hi * 4) * N + cbase0 + 4 * lo;
    const float* sqv_p = sq2 + cbase0 + 4 * lo;

    // per-lane online-softmax state; negative count
    float m[2][4], l[2][4], s[2][4];
    #pragma unroll
    for (int a = 0; a < 2; a++)
        #pragma unroll
        for (int r = 0; r < 4; r++) { m[a][r] = -1e30f; l[a][r] = 0.f; s[a][r] = 0.f; }
    uint32 cnt = 0;

    // ---- pipeline prologue: loads for tile 0 ----
    int4 mkv[2][4];
    uint4 vstg[4];
    f32x4 sqv;
    #pragma unroll
    for (int a = 0; a < 2; a++)
        #pragma unroll
        for (int r = 0; r < 4; r++)
            mkv[a][r] = *reinterpret_cast<const int4*>(simi_p + (size_t)(a * 16 + r) * N);
    #pragma unroll
    for (int it = 0; it < 4; it++)
        vstg[it] = *reinterpret_cast<const uint4*>(stg_p[it]);
    sqv = *reinterpret_cast<const f32x4*>(sqv_p);

    for (int t = 0; t < NTILES; t++) {
        __syncthreads();  // barrier A: prev tile's LDS reads done (+ drains our loads)
        // staging regs -> LDS (swizzled)
        #pragma unroll
        for (int it = 0; it < 4; it++)
            *reinterpret_cast<uint4*>(lds_p[it]) = vstg[it];
        __syncthreads();  // barrier B: LDS visible

        // convert tile-t masks (drained by barrier) to nibbles + count negs
        uint32 mb[2][4];
        #pragma unroll
        for (int a = 0; a < 2; a++)
            #pragma unroll
            for (int r = 0; r < 4; r++) {
                int4 v = mkv[a][r];
                uint32 nib = (uint32)(v.x == 1) | ((uint32)(v.y == 1) << 1) |
                             ((uint32)(v.z == 1) << 2) | ((uint32)(v.w == 1) << 3);
                mb[a][r] = nib;
                cnt += 4u - __popc(nib);
            }
        f32x4 sqv_t = sqv;

        // issue ALL tile-(t+1) loads now — they fly under the compute below
        if (t + 1 < NTILES) {
            const int* sp = simi_p + CT;
            #pragma unroll
            for (int a = 0; a < 2; a++)
                #pragma unroll
                for (int r = 0; r < 4; r++)
                    mkv[a][r] = *reinterpret_cast<const int4*>(sp + (size_t)(a * 16 + r) * N);
            #pragma unroll
            for (int it = 0; it < 4; it++)
                vstg[it] = *reinterpret_cast<const uint4*>(stg_p[it] + (size_t)(t + 1) * CT * D);
            sqv = *reinterpret_cast<const f32x4*>(sqv_p + (t + 1) * CT);
            simi_p = sp;
        }

        // MFMA: 32 rows x 64 cols; each B fragment feeds both A sets
        f32x4 acc[2][4];
        #pragma unroll
        for (int cf = 0; cf < 4; cf++) {
            acc[0][cf] = (f32x4){0.f, 0.f, 0.f, 0.f};
            acc[1][cf] = (f32x4){0.f, 0.f, 0.f, 0.f};
            const int brow = cf * 16 + lo;
            #pragma unroll
            for (int kk = 0; kk < 4; kk++) {
                int g = kk * 4 + hi;
                bf16x8 b = *reinterpret_cast<const bf16x8*>(
                    ldsB + brow * D + ((g ^ (brow & 15)) * 8));
                acc[0][cf] = __builtin_amdgcn_mfma_f32_16x16x32_bf16(afrag[0][kk], b, acc[0][cf], 0, 0, 0);
                acc[1][cf] = __builtin_amdgcn_mfma_f32_16x16x32_bf16(afrag[1][kk], b, acc[1][cf], 0, 0, 0);
            }
        }

        // logits lg = 2c - sq2[col] (row-constant sq1 dropped); per-lane
        // online max + rescale + accumulate — no cross-lane ops in the loop
        #pragma unroll
        for (int a = 0; a < 2; a++)
            #pragma unroll
            for (int r = 0; r < 4; r++) {
                float lg[4];
                #pragma unroll
                for (int cf = 0; cf < 4; cf++)
                    lg[cf] = 2.0f * acc[a][cf][r] - sqv_t[cf];
                float tm = fmaxf(fmaxf(lg[0], lg[1]), fmaxf(lg[2], lg[3]));
                float mn = fmaxf(m[a][r], tm);
                float al = __expf(m[a][r] - mn);
                m[a][r] = mn;
                float p[4];
                #pragma unroll
                for (int cf = 0; cf < 4; cf++) p[cf] = __expf(lg[cf] - mn);
                l[a][r] = l[a][r] * al + ((p[0] + p[1]) + (p[2] + p[3]));
                float sm = 0.f;
                #pragma unroll
                for (int cf = 0; cf < 4; cf++)
                    sm += ((mb[a][r] >> cf) & 1u) ? p[cf] : 0.f;
                s[a][r] = s[a][r] * al + sm;
            }
    }

    // end: cross-lane (lo group, 16 lanes) max + rescale + sum, once
    #pragma unroll
    for (int a = 0; a < 2; a++)
        #pragma unroll
        for (int r = 0; r < 4; r++) {
            float M = m[a][r];
            #pragma unroll
            for (int off = 1; off < 16; off <<= 1)
                M = fmaxf(M, __shfl_xor(M, off));
            float sc = __expf(m[a][r] - M);
            float L = l[a][r] * sc, S = s[a][r] * sc;
            #pragma unroll
            for (int off = 1; off < 16; off <<= 1) {
                L += __shfl_xor(L, off);
                S += __shfl_xor(S, off);
            }
            if (lo == 0) {
                int row = rbase + a * 16 + hi * 4 + r;
                int idx = chunk * N + row;
                pm[idx] = M; pl[idx] = L; ps[idx] = S;
            }
        }

    // negative count: wave reduce -> LDS -> one plain store per block
    #pragma unroll
    for (int off = 1; off < 64; off <<= 1) cnt += __shfl_xor(cnt, off);
    if (lane == 0) cred[wave] = cnt;
    __syncthreads();
    if (tid == 0)
        blockcnt[blockIdx.y * 64 + blockIdx.x] = cred[0] + cred[1] + cred[2] + cred[3];
}

// Merge per-chunk (m,l,s) partials per row; accumulate sum of s/l and the
// negative count (from 1024 per-block partials). 64 atomics total.
__global__ void merge_kernel(const float* __restrict__ pm, const float* __restrict__ pl,
                             const float* __restrict__ ps, const uint32* __restrict__ blockcnt,
                             float* __restrict__ s_acc, uint32* __restrict__ neg_acc) {
    const int row = blockIdx.x * 256 + threadIdx.x;
    float M = -1e30f;
    #pragma unroll
    for (int k = 0; k < NCHUNK; k++) M = fmaxf(M, pm[k * N + row]);
    float L = 0.f, S = 0.f;
    #pragma unroll
    for (int k = 0; k < NCHUNK; k++) {
        float e = __expf(pm[k * N + row] - M);
        L += pl[k * N + row] * e;
        S += ps[k * N + row] * e;
    }
    float r = S / L;
    uint32 pc = (threadIdx.x < 32) ? blockcnt[blockIdx.x * 32 + threadIdx.x] : 0u;
    #pragma unroll
    for (int off = 32; off > 0; off >>= 1) {
        r  += __shfl_xor(r, off);
        pc += __shfl_xor(pc, off);
    }
    __shared__ float red[4];
    __shared__ uint32 redp[4];
    int lane = threadIdx.x & 63, w = threadIdx.x >> 6;
    if (lane == 0) { red[w] = r; redp[w] = pc; }
    __syncthreads();
    if (threadIdx.x == 0) {
        atomicAdd(s_acc, red[0] + red[1] + red[2] + red[3]);
        atomicAdd(neg_acc, redp[0] + redp[1] + redp[2] + redp[3]);
    }
}

__global__ void final_kernel(const float* __restrict__ s_acc, const uint32* __restrict__ neg_acc,
                             float* __restrict__ out) {
    double S = (double)s_acc[0];
    double C = (double)neg_acc[0];   // count(simi != 1), counted directly
    double n = (double)N;
    out[0] = (float)((2.0 * S + C - n) / (n * n));
}

extern "C" void kernel_launch(void* const* d_in, const int* in_sizes, int n_in,
                              void* d_out, int out_size, void* d_ws, size_t ws_size,
                              hipStream_t stream) {
    const float* f1   = (const float*)d_in[0];
    const float* f2   = (const float*)d_in[1];
    const int*   simi = (const int*)d_in[2];
    float* out = (float*)d_out;
    char* ws = (char*)d_ws;

    float*  acc_s    = (float*)(ws + OFF_ACC);
    uint32* acc_n    = (uint32*)(ws + OFF_ACC + 4);
    float*  sq2      = (float*)(ws + OFF_SQ2);
    uint32* blockcnt = (uint32*)(ws + OFF_BCNT);
    float*  pm       = (float*)(ws + OFF_M);
    float*  pl       = (float*)(ws + OFF_L);
    float*  ps       = (float*)(ws + OFF_S);
    unsigned short* f1b = (unsigned short*)(ws + OFF_F1);
    unsigned short* f2b = (unsigned short*)(ws + OFF_F2);

    hipMemsetAsync(ws + OFF_ACC, 0, 64, stream);
    prep_kernel<<<256, 256, 0, stream>>>(f1, f2, f1b, f2b, sq2);
    main_kernel<<<dim3(N / RT, NCHUNK), 256, 0, stream>>>(f1b, f2b, sq2, simi,
                                                          pm, pl, ps, blockcnt);
    merge_kernel<<<N / 256, 256, 0, stream>>>(pm, pl, ps, blockcnt, acc_s, acc_n);
    final_kernel<<<1, 1, 0, stream>>>(acc_s, acc_n, out);
}

// Round 11
// 426.184 us; speedup vs baseline: 1.0022x; 1.0022x over previous
//
#include <hip/hip_runtime.h>
#include <hip/hip_bf16.h>
#include <stdint.h>

#define N 8192
#define D 128
#define NCHUNK 16
#define CHUNK (N / NCHUNK)      // 512 cols per chunk
#define RT 64                   // rows per block (4 waves x 16)
#define CT 64                   // cols per LDS tile
#define NTILES (CHUNK / CT)     // 8
#define NBLK (N / RT * NCHUNK)  // 2048 main blocks

typedef short bf16x8 __attribute__((ext_vector_type(8)));
typedef float f32x4 __attribute__((ext_vector_type(4)));
typedef unsigned int uint32;

// ---- workspace layout (bytes) ----
#define OFF_ACC   0u                          // [0] float S_sum, [4] uint32 C_count
#define OFF_SQ2   1024u                       // 8192 floats
#define OFF_BCNT  (OFF_SQ2 + N * 4u)          // NBLK uint32 per-block negative counts
#define OFF_M     (OFF_BCNT + NBLK * 4u)      // NCHUNK*N floats (per-chunk row max)
#define OFF_L     (OFF_M + NCHUNK * N * 4u)
#define OFF_S     (OFF_L + NCHUNK * N * 4u)
#define OFF_F1    (OFF_S + NCHUNK * N * 4u)   // feat1 bf16
#define OFF_F2    (OFF_F1 + N * D * 2u)       // feat2 bf16

// async global->LDS, 16B per lane; LDS dest = uniform base + lane*16
#define GLLDS16(gp, lp)                                                        \
    __builtin_amdgcn_global_load_lds(                                          \
        (const __attribute__((address_space(1))) uint32*)(gp),                 \
        (__attribute__((address_space(3))) uint32*)(lp), 16, 0, 0)

// Convert feats to bf16; compute sq2[j] = ||feat2_j||^2.
__global__ __launch_bounds__(256)
void prep_kernel(const float* __restrict__ f1, const float* __restrict__ f2,
                 unsigned short* __restrict__ f1b, unsigned short* __restrict__ f2b,
                 float* __restrict__ sq2) {
    const int w    = blockIdx.x * 4 + (threadIdx.x >> 6);  // 0..1023
    const int lane = threadIdx.x & 63;
    for (int row = w; row < N; row += 1024) {
        float a0 = f1[row * D + lane];
        float a1 = f1[row * D + 64 + lane];
        float b0 = f2[row * D + lane];
        float b1 = f2[row * D + 64 + lane];
        __hip_bfloat16 t;
        t = __float2bfloat16(a0); f1b[row * D + lane]      = *(unsigned short*)&t;
        t = __float2bfloat16(a1); f1b[row * D + 64 + lane] = *(unsigned short*)&t;
        t = __float2bfloat16(b0); f2b[row * D + lane]      = *(unsigned short*)&t;
        t = __float2bfloat16(b1); f2b[row * D + 64 + lane] = *(unsigned short*)&t;
        float ss = b0 * b0 + b1 * b1;
        #pragma unroll
        for (int off = 32; off > 0; off >>= 1) ss += __shfl_xor(ss, off);
        if (lane == 0) sq2[row] = ss;
    }
}

// FUSED GEMM + online softmax + raw-simi masking + negative count.
// R11: R10's pipeline schedule (all tile-(t+1) loads issue after barrier B of
// tile t, drain at tile t+1's barrier A under a full compute phase of cover)
// but with ZERO register cost for the heavy prefetch: simi masks go straight
// to LDS via async global_load_lds (R10 held them in 32 VGPRs -> 105 MB/launch
// scratch spill, occupancy 27%). Per-wave state also halved (RT 128->64,
// 1 A-set). LDS: 16 KB B-tile + 2x16 KB mask dbuf = 48 KB -> 3 blocks/CU.
// Column permutation c(q)=4*(q&15)+(q>>4): acc[cf] lane lo <-> global col
// cbase+4*lo+cf -> one int4 simi load per row per tile; softmax perm-invariant.
__global__ __launch_bounds__(256)
void main_kernel(const unsigned short* __restrict__ f1b,
                 const unsigned short* __restrict__ f2b,
                 const float* __restrict__ sq2,
                 const int* __restrict__ simi,
                 float* __restrict__ pm, float* __restrict__ pl, float* __restrict__ ps,
                 uint32* __restrict__ blockcnt) {
    __shared__ unsigned short ldsB[CT * D];          // 16 KB, XOR-swizzled
    __shared__ uint32 maskMem[2 * 4 * 4 * 256];      // 32 KB: [parity][wave][r][lane*4]
    __shared__ uint32 cred[4];

    const int tid  = threadIdx.x;
    const int wave = tid >> 6;
    const int lane = tid & 63;
    const int lo   = lane & 15;
    const int hi   = lane >> 4;

    const int rowtile = blockIdx.x;       // 0..127
    const int chunk   = blockIdx.y;       // 0..15
    const int rbase   = rowtile * RT + wave * 16;
    const int cbase0  = chunk * CHUNK;

    // A fragments: 16 rows, full K=128, resident for the sweep.
    bf16x8 afrag[4];
    {
        const unsigned short* ap = f1b + (size_t)(rbase + lo) * D + hi * 8;
        #pragma unroll
        for (int kk = 0; kk < 4; kk++)
            afrag[kk] = *reinterpret_cast<const bf16x8*>(ap + kk * 32);
    }

    const int sq_ = (tid >> 4);           // staging: position within 16-group
    const int sg_ = tid & 15;             // staging: 16B chunk index
    // staging source pointers (col c(q) fixed per thread per it)
    const unsigned short* stg_p[4];
    unsigned short* lds_p[4];
    #pragma unroll
    for (int it = 0; it < 4; it++) {
        int q = it * 16 + sq_;
        int c = 4 * (q & 15) + (q >> 4);
        stg_p[it] = f2b + (size_t)(cbase0 + c) * D + sg_ * 8;
        lds_p[it] = ldsB + q * D + ((sg_ ^ (q & 15)) * 8);
    }

    // simi pointer: row rbase+hi*4+r, cols cbase0 + 4*lo (16B per lane)
    const int* simi_p = simi + (size_t)(rbase + hi * 4) * N + cbase0 + 4 * lo;
    const float* sqv_p = sq2 + cbase0 + 4 * lo;
    // mask LDS bases (uniform per wave): parity p, row-slot r
    uint32* mbase[2];
    mbase[0] = maskMem + wave * 4 * 256;
    mbase[1] = maskMem + (4 + wave) * 4 * 256;

    // per-lane online-softmax state; negative count
    float m[4], l[4], s[4];
    #pragma unroll
    for (int r = 0; r < 4; r++) { m[r] = -1e30f; l[r] = 0.f; s[r] = 0.f; }
    uint32 cnt = 0;

    // ---- pipeline prologue: tile-0 loads ----
    #pragma unroll
    for (int r = 0; r < 4; r++)
        GLLDS16(simi_p + (size_t)r * N, mbase[0] + r * 256);
    uint4 vstg[4];
    #pragma unroll
    for (int it = 0; it < 4; it++)
        vstg[it] = *reinterpret_cast<const uint4*>(stg_p[it]);
    f32x4 sqv = *reinterpret_cast<const f32x4*>(sqv_p);

    for (int t = 0; t < NTILES; t++) {
        __syncthreads();  // barrier A: prev LDS reads done + drains tile-t loads
        #pragma unroll
        for (int it = 0; it < 4; it++)
            *reinterpret_cast<uint4*>(lds_p[it]) = vstg[it];
        __syncthreads();  // barrier B: LDS visible

        // read tile-t masks from LDS, convert to nibbles, count negatives
        const uint32* mk = mbase[t & 1];
        uint32 mb[4];
        #pragma unroll
        for (int r = 0; r < 4; r++) {
            int4 v = *reinterpret_cast<const int4*>(mk + r * 256 + lane * 4);
            uint32 nib = (uint32)(v.x == 1) | ((uint32)(v.y == 1) << 1) |
                         ((uint32)(v.z == 1) << 2) | ((uint32)(v.w == 1) << 3);
            mb[r] = nib;
            cnt += 4u - __popc(nib);
        }
        f32x4 sqv_t = sqv;

        // issue ALL tile-(t+1) loads now — fly under MFMA+exp below
        if (t + 1 < NTILES) {
            const int* sp = simi_p + CT;
            #pragma unroll
            for (int r = 0; r < 4; r++)
                GLLDS16(sp + (size_t)r * N, mbase[(t + 1) & 1] + r * 256);
            #pragma unroll
            for (int it = 0; it < 4; it++)
                vstg[it] = *reinterpret_cast<const uint4*>(stg_p[it] + (size_t)(t + 1) * CT * D);
            sqv = *reinterpret_cast<const f32x4*>(sqv_p + (t + 1) * CT);
            simi_p = sp;
        }

        // MFMA: 16 rows x 64 cols
        f32x4 acc[4];
        #pragma unroll
        for (int cf = 0; cf < 4; cf++) {
            acc[cf] = (f32x4){0.f, 0.f, 0.f, 0.f};
            const int brow = cf * 16 + lo;
            #pragma unroll
            for (int kk = 0; kk < 4; kk++) {
                int g = kk * 4 + hi;
                bf16x8 b = *reinterpret_cast<const bf16x8*>(
                    ldsB + brow * D + ((g ^ (brow & 15)) * 8));
                acc[cf] = __builtin_amdgcn_mfma_f32_16x16x32_bf16(afrag[kk], b, acc[cf], 0, 0, 0);
            }
        }

        // logits lg = 2c - sq2[col] (row-constant sq1 dropped); per-lane
        // online max + rescale + accumulate — no cross-lane ops in the loop
        #pragma unroll
        for (int r = 0; r < 4; r++) {
            float lg[4];
            #pragma unroll
            for (int cf = 0; cf < 4; cf++)
                lg[cf] = 2.0f * acc[cf][r] - sqv_t[cf];
            float tm = fmaxf(fmaxf(lg[0], lg[1]), fmaxf(lg[2], lg[3]));
            float mn = fmaxf(m[r], tm);
            float al = __expf(m[r] - mn);
            m[r] = mn;
            float p[4];
            #pragma unroll
            for (int cf = 0; cf < 4; cf++) p[cf] = __expf(lg[cf] - mn);
            l[r] = l[r] * al + ((p[0] + p[1]) + (p[2] + p[3]));
            float sm = 0.f;
            #pragma unroll
            for (int cf = 0; cf < 4; cf++)
                sm += ((mb[r] >> cf) & 1u) ? p[cf] : 0.f;
            s[r] = s[r] * al + sm;
        }
    }

    // end: cross-lane (lo group, 16 lanes) max + rescale + sum, once
    #pragma unroll
    for (int r = 0; r < 4; r++) {
        float M = m[r];
        #pragma unroll
        for (int off = 1; off < 16; off <<= 1)
            M = fmaxf(M, __shfl_xor(M, off));
        float sc = __expf(m[r] - M);
        float L = l[r] * sc, S = s[r] * sc;
        #pragma unroll
        for (int off = 1; off < 16; off <<= 1) {
            L += __shfl_xor(L, off);
            S += __shfl_xor(S, off);
        }
        if (lo == 0) {
            int row = rbase + hi * 4 + r;
            int idx = chunk * N + row;
            pm[idx] = M; pl[idx] = L; ps[idx] = S;
        }
    }

    // negative count: wave reduce -> LDS -> one plain store per block
    #pragma unroll
    for (int off = 1; off < 64; off <<= 1) cnt += __shfl_xor(cnt, off);
    if (lane == 0) cred[wave] = cnt;
    __syncthreads();
    if (tid == 0)
        blockcnt[blockIdx.y * 128 + blockIdx.x] = cred[0] + cred[1] + cred[2] + cred[3];
}

// Merge per-chunk (m,l,s) partials per row; accumulate sum of s/l and the
// negative count (from 2048 per-block partials). 64 atomics total.
__global__ void merge_kernel(const float* __restrict__ pm, const float* __restrict__ pl,
                             const float* __restrict__ ps, const uint32* __restrict__ blockcnt,
                             float* __restrict__ s_acc, uint32* __restrict__ neg_acc) {
    const int row = blockIdx.x * 256 + threadIdx.x;
    float M = -1e30f;
    #pragma unroll
    for (int k = 0; k < NCHUNK; k++) M = fmaxf(M, pm[k * N + row]);
    float L = 0.f, S = 0.f;
    #pragma unroll
    for (int k = 0; k < NCHUNK; k++) {
        float e = __expf(pm[k * N + row] - M);
        L += pl[k * N + row] * e;
        S += ps[k * N + row] * e;
    }
    float r = S / L;
    uint32 pc = (threadIdx.x < 64) ? blockcnt[blockIdx.x * 64 + threadIdx.x] : 0u;
    #pragma unroll
    for (int off = 32; off > 0; off >>= 1) {
        r  += __shfl_xor(r, off);
        pc += __shfl_xor(pc, off);
    }
    __shared__ float red[4];
    __shared__ uint32 redp[4];
    int lane = threadIdx.x & 63, w = threadIdx.x >> 6;
    if (lane == 0) { red[w] = r; redp[w] = pc; }
    __syncthreads();
    if (threadIdx.x == 0) {
        atomicAdd(s_acc, red[0] + red[1] + red[2] + red[3]);
        atomicAdd(neg_acc, redp[0] + redp[1] + redp[2] + redp[3]);
    }
}

__global__ void final_kernel(const float* __restrict__ s_acc, const uint32* __restrict__ neg_acc,
                             float* __restrict__ out) {
    double S = (double)s_acc[0];
    double C = (double)neg_acc[0];   // count(simi != 1), counted directly
    double n = (double)N;
    out[0] = (float)((2.0 * S + C - n) / (n * n));
}

extern "C" void kernel_launch(void* const* d_in, const int* in_sizes, int n_in,
                              void* d_out, int out_size, void* d_ws, size_t ws_size,
                              hipStream_t stream) {
    const float* f1   = (const float*)d_in[0];
    const float* f2   = (const float*)d_in[1];
    const int*   simi = (const int*)d_in[2];
    float* out = (float*)d_out;
    char* ws = (char*)d_ws;

    float*  acc_s    = (float*)(ws + OFF_ACC);
    uint32* acc_n    = (uint32*)(ws + OFF_ACC + 4);
    float*  sq2      = (float*)(ws + OFF_SQ2);
    uint32* blockcnt = (uint32*)(ws + OFF_BCNT);
    float*  pm       = (float*)(ws + OFF_M);
    float*  pl       = (float*)(ws + OFF_L);
    float*  ps       = (float*)(ws + OFF_S);
    unsigned short* f1b = (unsigned short*)(ws + OFF_F1);
    unsigned short* f2b = (unsigned short*)(ws + OFF_F2);

    hipMemsetAsync(ws + OFF_ACC, 0, 64, stream);
    prep_kernel<<<256, 256, 0, stream>>>(f1, f2, f1b, f2b, sq2);
    main_kernel<<<dim3(N / RT, NCHUNK), 256, 0, stream>>>(f1b, f2b, sq2, simi,
                                                          pm, pl, ps, blockcnt);
    merge_kernel<<<N / 256, 256, 0, stream>>>(pm, pl, ps, blockcnt, acc_s, acc_n);
    final_kernel<<<1, 1, 0, stream>>>(acc_s, acc_n, out);
}

// Round 12
// 419.644 us; speedup vs baseline: 1.0179x; 1.0156x over previous
//
#include <hip/hip_runtime.h>
#include <hip/hip_bf16.h>
#include <stdint.h>

#define N 8192
#define D 128
#define NCHUNK 8
#define CHUNK (N / NCHUNK)      // 1024 cols per chunk
#define RT 64                   // rows per block (4 waves x 16)
#define CT 64                   // cols per tile
#define NTILES (CHUNK / CT)     // 16
#define NBLK (N / RT * NCHUNK)  // 1024 main blocks

typedef short bf16x8 __attribute__((ext_vector_type(8)));
typedef float f32x4 __attribute__((ext_vector_type(4)));
typedef unsigned int uint32;

// ---- workspace layout (bytes) ----
#define OFF_ACC   0u                          // [0] float S_sum, [4] uint32 C_count
#define OFF_SQ2   1024u                       // 8192 floats
#define OFF_BCNT  (OFF_SQ2 + N * 4u)          // NBLK uint32 per-block negative counts
#define OFF_M     (OFF_BCNT + NBLK * 4u)      // NCHUNK*N floats
#define OFF_L     (OFF_M + NCHUNK * N * 4u)
#define OFF_S     (OFF_L + NCHUNK * N * 4u)
#define OFF_F1    (OFF_S + NCHUNK * N * 4u)   // feat1 bf16 row-major
#define OFF_F2T   (OFF_F1 + N * D * 2u)       // feat2 bf16, MFMA B-fragment order

// Convert feat1 to bf16 (row-major); compute sq2[j] = ||feat2_j||^2.
__global__ __launch_bounds__(256)
void prep_kernel(const float* __restrict__ f1, const float* __restrict__ f2,
                 unsigned short* __restrict__ f1b, float* __restrict__ sq2) {
    const int w    = blockIdx.x * 4 + (threadIdx.x >> 6);  // 0..1023
    const int lane = threadIdx.x & 63;
    for (int row = w; row < N; row += 1024) {
        float a0 = f1[row * D + lane];
        float a1 = f1[row * D + 64 + lane];
        float b0 = f2[row * D + lane];
        float b1 = f2[row * D + 64 + lane];
        __hip_bfloat16 t;
        t = __float2bfloat16(a0); f1b[row * D + lane]      = *(unsigned short*)&t;
        t = __float2bfloat16(a1); f1b[row * D + 64 + lane] = *(unsigned short*)&t;
        float ss = b0 * b0 + b1 * b1;
        #pragma unroll
        for (int off = 32; off > 0; off >>= 1) ss += __shfl_xor(ss, off);
        if (lane == 0) sq2[row] = ss;
    }
}

// Build f2T: feat2 in exact MFMA B-fragment order, so main's B loads are
// fully-coalesced 1KB global_load_dwordx4 (R7's direct-global B failed on
// 16-way scattered segments; this fixes that). Per 64-col tile t64, per
// (cf,kk) fragment-block: lane (lo,hi) holds col t64*64 + 4*lo + cf
// (permuted order — matches R9's proven mask/sqv int4 mapping), k-chunk
// g=kk*4+hi (8 bf16). short-offset = ((t64*16 + cf*4 + kk)*512) + lane*8.
__global__ __launch_bounds__(256)
void prep2_kernel(const float* __restrict__ f2, unsigned short* __restrict__ f2T) {
    const int t64  = blockIdx.x;          // 0..127
    const int cf   = threadIdx.x >> 6;    // 0..3
    const int lane = threadIdx.x & 63;
    const int lo   = lane & 15;
    const int hi   = lane >> 4;
    const int col  = t64 * 64 + 4 * lo + cf;
    #pragma unroll
    for (int kk = 0; kk < 4; kk++) {
        const float* src = f2 + (size_t)col * D + (kk * 4 + hi) * 8;
        bf16x8 o;
        #pragma unroll
        for (int j = 0; j < 8; j++) {
            __hip_bfloat16 t = __float2bfloat16(src[j]);
            o[j] = *reinterpret_cast<short*>(&t);
        }
        *reinterpret_cast<bf16x8*>(
            f2T + ((size_t)t64 * 16 + cf * 4 + kk) * 512 + lane * 8) = o;
    }
}

// FUSED GEMM + per-lane online softmax + raw-simi masking + negative count.
// R12: BARRIER-FREE K-loop. No LDS, no __syncthreads in the loop — so no
// forced s_waitcnt vmcnt(0) drains (the structural stall of R5..R11; every
// barrier-containing variant plateaued at main>=130us). B fragments come from
// L2-resident f2T as coalesced 1KB loads; masks prefetched 1 tile ahead in
// VGPRs (16 regs — affordable now that staging regs are gone); compiler emits
// fine-grained vmcnt(N) per dependency. Each wave is an independent job:
// 16 rows x 1024 cols.
__global__ __launch_bounds__(256)
void main_kernel(const unsigned short* __restrict__ f1b,
                 const unsigned short* __restrict__ f2T,
                 const float* __restrict__ sq2,
                 const int* __restrict__ simi,
                 float* __restrict__ pm, float* __restrict__ pl, float* __restrict__ ps,
                 uint32* __restrict__ blockcnt) {
    __shared__ uint32 cred[4];

    const int tid  = threadIdx.x;
    const int wave = tid >> 6;
    const int lane = tid & 63;
    const int lo   = lane & 15;
    const int hi   = lane >> 4;

    const int rbase  = blockIdx.x * RT + wave * 16;   // 16 rows per wave
    const int chunk  = blockIdx.y;                    // 0..7
    const int cbase0 = chunk * CHUNK;
    const int T0     = chunk * NTILES;                // global tile64 base

    // A fragments: 16 rows, full K=128, resident for the sweep.
    bf16x8 afrag[4];
    {
        const unsigned short* ap = f1b + (size_t)(rbase + lo) * D + hi * 8;
        #pragma unroll
        for (int kk = 0; kk < 4; kk++)
            afrag[kk] = *reinterpret_cast<const bf16x8*>(ap + kk * 32);
    }

    // mask/sqv pointers: lane (lo,hi), row-slot r -> row rbase+hi*4+r,
    // cols cbase0 + 4*lo .. +3 (matches f2T's baked permutation)
    const int* simi_p  = simi + (size_t)(rbase + hi * 4) * N + cbase0 + 4 * lo;
    const float* sqv_p = sq2 + cbase0 + 4 * lo;
    const unsigned short* bT = f2T + (size_t)T0 * 8192 + lane * 8;

    float m[4], l[4], s[4];
    #pragma unroll
    for (int r = 0; r < 4; r++) { m[r] = -1e30f; l[r] = 0.f; s[r] = 0.f; }
    uint32 cnt = 0;

    // prologue: tile-0 masks + sqv
    int4 mkv[4];
    #pragma unroll
    for (int r = 0; r < 4; r++)
        mkv[r] = *reinterpret_cast<const int4*>(simi_p + (size_t)r * N);
    f32x4 sqv = *reinterpret_cast<const f32x4*>(sqv_p);

    for (int t = 0; t < NTILES; t++) {
        // consume tile-t masks (loaded a full tile ago)
        uint32 mb[4];
        #pragma unroll
        for (int r = 0; r < 4; r++) {
            int4 v = mkv[r];
            uint32 nib = (uint32)(v.x == 1) | ((uint32)(v.y == 1) << 1) |
                         ((uint32)(v.z == 1) << 2) | ((uint32)(v.w == 1) << 3);
            mb[r] = nib;
            cnt += 4u - __popc(nib);
        }
        f32x4 sqv_t = sqv;

        // prefetch tile-(t+1) masks + sqv — fly under MFMA+exp below
        if (t + 1 < NTILES) {
            simi_p += CT;
            #pragma unroll
            for (int r = 0; r < 4; r++)
                mkv[r] = *reinterpret_cast<const int4*>(simi_p + (size_t)r * N);
            sqv = *reinterpret_cast<const f32x4*>(sqv_p + (t + 1) * CT);
        }

        // MFMA: 16 rows x 64 cols; B frags are coalesced 1KB L2 loads
        f32x4 acc[4];
        #pragma unroll
        for (int cf = 0; cf < 4; cf++) {
            acc[cf] = (f32x4){0.f, 0.f, 0.f, 0.f};
            const unsigned short* bp = bT + ((size_t)t * 16 + cf * 4) * 512;
            #pragma unroll
            for (int kk = 0; kk < 4; kk++) {
                bf16x8 b = *reinterpret_cast<const bf16x8*>(bp + kk * 512);
                acc[cf] = __builtin_amdgcn_mfma_f32_16x16x32_bf16(afrag[kk], b, acc[cf], 0, 0, 0);
            }
        }

        // logits lg = 2c - sq2[col] (row-constant sq1 dropped); per-lane
        // online max + rescale + accumulate — no cross-lane ops in the loop
        #pragma unroll
        for (int r = 0; r < 4; r++) {
            float lg[4];
            #pragma unroll
            for (int cf = 0; cf < 4; cf++)
                lg[cf] = 2.0f * acc[cf][r] - sqv_t[cf];
            float tm = fmaxf(fmaxf(lg[0], lg[1]), fmaxf(lg[2], lg[3]));
            float mn = fmaxf(m[r], tm);
            float al = __expf(m[r] - mn);
            m[r] = mn;
            float p[4];
            #pragma unroll
            for (int cf = 0; cf < 4; cf++) p[cf] = __expf(lg[cf] - mn);
            l[r] = l[r] * al + ((p[0] + p[1]) + (p[2] + p[3]));
            float sm = 0.f;
            #pragma unroll
            for (int cf = 0; cf < 4; cf++)
                sm += ((mb[r] >> cf) & 1u) ? p[cf] : 0.f;
            s[r] = s[r] * al + sm;
        }
    }

    // end: cross-lane (lo group, 16 lanes) max + rescale + sum, once
    #pragma unroll
    for (int r = 0; r < 4; r++) {
        float M = m[r];
        #pragma unroll
        for (int off = 1; off < 16; off <<= 1)
            M = fmaxf(M, __shfl_xor(M, off));
        float sc = __expf(m[r] - M);
        float L = l[r] * sc, S = s[r] * sc;
        #pragma unroll
        for (int off = 1; off < 16; off <<= 1) {
            L += __shfl_xor(L, off);
            S += __shfl_xor(S, off);
        }
        if (lo == 0) {
            int row = rbase + hi * 4 + r;
            int idx = chunk * N + row;
            pm[idx] = M; pl[idx] = L; ps[idx] = S;
        }
    }

    // negative count: wave reduce -> LDS -> one plain store per block
    #pragma unroll
    for (int off = 1; off < 64; off <<= 1) cnt += __shfl_xor(cnt, off);
    if (lane == 0) cred[wave] = cnt;
    __syncthreads();
    if (tid == 0)
        blockcnt[blockIdx.y * 128 + blockIdx.x] = cred[0] + cred[1] + cred[2] + cred[3];
}

// Merge per-chunk (m,l,s) partials per row; accumulate sum of s/l and the
// negative count (1024 per-block partials). 64 atomics total.
__global__ void merge_kernel(const float* __restrict__ pm, const float* __restrict__ pl,
                             const float* __restrict__ ps, const uint32* __restrict__ blockcnt,
                             float* __restrict__ s_acc, uint32* __restrict__ neg_acc) {
    const int row = blockIdx.x * 256 + threadIdx.x;
    float M = -1e30f;
    #pragma unroll
    for (int k = 0; k < NCHUNK; k++) M = fmaxf(M, pm[k * N + row]);
    float L = 0.f, S = 0.f;
    #pragma unroll
    for (int k = 0; k < NCHUNK; k++) {
        float e = __expf(pm[k * N + row] - M);
        L += pl[k * N + row] * e;
        S += ps[k * N + row] * e;
    }
    float r = S / L;
    uint32 pc = (threadIdx.x < 32) ? blockcnt[blockIdx.x * 32 + threadIdx.x] : 0u;
    #pragma unroll
    for (int off = 32; off > 0; off >>= 1) {
        r  += __shfl_xor(r, off);
        pc += __shfl_xor(pc, off);
    }
    __shared__ float red[4];
    __shared__ uint32 redp[4];
    int lane = threadIdx.x & 63, w = threadIdx.x >> 6;
    if (lane == 0) { red[w] = r; redp[w] = pc; }
    __syncthreads();
    if (threadIdx.x == 0) {
        atomicAdd(s_acc, red[0] + red[1] + red[2] + red[3]);
        atomicAdd(neg_acc, redp[0] + redp[1] + redp[2] + redp[3]);
    }
}

__global__ void final_kernel(const float* __restrict__ s_acc, const uint32* __restrict__ neg_acc,
                             float* __restrict__ out) {
    double S = (double)s_acc[0];
    double C = (double)neg_acc[0];   // count(simi != 1)
    double n = (double)N;
    out[0] = (float)((2.0 * S + C - n) / (n * n));
}

extern "C" void kernel_launch(void* const* d_in, const int* in_sizes, int n_in,
                              void* d_out, int out_size, void* d_ws, size_t ws_size,
                              hipStream_t stream) {
    const float* f1   = (const float*)d_in[0];
    const float* f2   = (const float*)d_in[1];
    const int*   simi = (const int*)d_in[2];
    float* out = (float*)d_out;
    char* ws = (char*)d_ws;

    float*  acc_s    = (float*)(ws + OFF_ACC);
    uint32* acc_n    = (uint32*)(ws + OFF_ACC + 4);
    float*  sq2      = (float*)(ws + OFF_SQ2);
    uint32* blockcnt = (uint32*)(ws + OFF_BCNT);
    float*  pm       = (float*)(ws + OFF_M);
    float*  pl       = (float*)(ws + OFF_L);
    float*  ps       = (float*)(ws + OFF_S);
    unsigned short* f1b = (unsigned short*)(ws + OFF_F1);
    unsigned short* f2T = (unsigned short*)(ws + OFF_F2T);

    hipMemsetAsync(ws + OFF_ACC, 0, 64, stream);
    prep_kernel<<<256, 256, 0, stream>>>(f1, f2, f1b, sq2);
    prep2_kernel<<<N / 64, 256, 0, stream>>>(f2, f2T);
    main_kernel<<<dim3(N / RT, NCHUNK), 256, 0, stream>>>(f1b, f2T, sq2, simi,
                                                          pm, pl, ps, blockcnt);
    merge_kernel<<<N / 256, 256, 0, stream>>>(pm, pl, ps, blockcnt, acc_s, acc_n);
    final_kernel<<<1, 1, 0, stream>>>(acc_s, acc_n, out);
}